// Round 2
// baseline (180.301 us; speedup 1.0000x reference)
//
#include <hip/hip_runtime.h>
#include <hip/hip_bf16.h>

// Problem: GraphAttentionLayer  B=16, L=128, DIN=768, DH=300, DE=100
// Device dtypes: float tensors = FP32 (NaN evidence round 1), adj = int32, out = fp32.
//
// Pipeline:
//   k_small : c[d] = sum_k elw[k]*emw[k,d]; c0; band-sparse V (<=4 weights/row)
//   k_gemm  : h = x @ W   (split-K=2 partials, LDS-tiled vector-fp32 GEMM)
//   k_red   : h = hp0+hp1 ; e2[m] = h[m,:]·a[300:600]
//   k_attn  : per (b,i): e1 (sparse V), +e2[b,j], leakyrelu, *sigmoid(ee·c+c0),
//             mask by adj, softmax over j, out = h_row + att @ h[b]

#define L 128
#define DH 300
#define DIN 768
#define DE 100

// ---------------- k_small: c vector, c0, band-sparse V ----------------
__global__ __launch_bounds__(256) void k_small(
    const float* __restrict__ A,    // a (600,1)
    const float* __restrict__ EMW,  // edge_map_w (300,100)
    const float* __restrict__ EMB,  // edge_map_b (300,)
    const float* __restrict__ ELW,  // edge_lin_w (1,300)
    const float* __restrict__ ELB,  // edge_lin_b (1,)
    float* __restrict__ CV, float* __restrict__ C0,
    float* __restrict__ VW, int* __restrict__ VCOL)
{
    int t = threadIdx.x;
    if (blockIdx.x == 0) {
        if (t < DE) {
            float s = 0.f;
            for (int k = 0; k < DH; ++k)
                s += ELW[k] * EMW[k * DE + t];
            CV[t] = s;
        } else if (t == DE) {
            float s = 0.f;
            for (int k = 0; k < DH; ++k)
                s += ELW[k] * EMB[k];
            C0[0] = s + ELB[0];
        }
    } else {
        if (t < L) {
            int base = t * DH;
            int cm = base >> 7;           // // L, L=128
            float w0 = 0.f, w1 = 0.f, w2 = 0.f, w3 = 0.f;
            for (int j = 0; j < DH; ++j) {
                int u = ((base + j) >> 7) - cm;
                float av = A[j];
                w0 += (u == 0) ? av : 0.f;
                w1 += (u == 1) ? av : 0.f;
                w2 += (u == 2) ? av : 0.f;
                w3 += (u == 3) ? av : 0.f;
            }
            VCOL[t] = cm;
            VW[t * 4 + 0] = w0; VW[t * 4 + 1] = w1;
            VW[t * 4 + 2] = w2; VW[t * 4 + 3] = w3;
        }
    }
}

// ---------------- k_gemm: h = x @ W, split-K=2 ----------------
// grid (4 colTiles, 32 rowTiles, 2 kSlices), 256 threads
// tile 64 (M) x 80 (N), K-step 32, micro 4x5 per thread
__global__ __launch_bounds__(256) void k_gemm(
    const float* __restrict__ X,   // (2048, 768)
    const float* __restrict__ Wm,  // (768, 300)
    float* __restrict__ HP)        // 2 x (2048*300) fp32 partials
{
    __shared__ float As[32 * 65];     // As[k*65 + row], padded
    __shared__ float Bs[32 * 80];     // Bs[k*80 + col]
    int t = threadIdx.x;
    int ty = t >> 4, tx = t & 15;
    int r0 = blockIdx.y * 64;
    int c0 = blockIdx.x * 80;
    int kz = blockIdx.z;
    int kbase = kz * 384;

    float acc[4][5];
#pragma unroll
    for (int r = 0; r < 4; ++r)
#pragma unroll
        for (int c = 0; c < 5; ++c) acc[r][c] = 0.f;

    for (int ks = 0; ks < 384; ks += 32) {
        int kk = kbase + ks;
        // stage A tile 64x32 (transposed in LDS)
#pragma unroll
        for (int s = 0; s < 8; ++s) {
            int idx = t + 256 * s;
            int row = idx >> 5, k = idx & 31;
            As[k * 65 + row] = X[(size_t)(r0 + row) * DIN + kk + k];
        }
        // stage B tile 32x80 (scalar, guarded)
#pragma unroll
        for (int s = 0; s < 10; ++s) {
            int idx = t + 256 * s;   // < 2560 always
            int k = idx / 80, c = idx % 80;
            int col = c0 + c;
            Bs[k * 80 + c] = (col < DH) ? Wm[(size_t)(kk + k) * DH + col] : 0.f;
        }
        __syncthreads();
#pragma unroll
        for (int k = 0; k < 32; ++k) {
            float av[4], bv[5];
#pragma unroll
            for (int r = 0; r < 4; ++r) av[r] = As[k * 65 + ty * 4 + r];
#pragma unroll
            for (int c = 0; c < 5; ++c) bv[c] = Bs[k * 80 + tx * 5 + c];
#pragma unroll
            for (int r = 0; r < 4; ++r)
#pragma unroll
                for (int c = 0; c < 5; ++c)
                    acc[r][c] = fmaf(av[r], bv[c], acc[r][c]);
        }
        __syncthreads();
    }
    float* out = HP + (size_t)kz * (2048 * DH);
#pragma unroll
    for (int r = 0; r < 4; ++r) {
        int row = r0 + ty * 4 + r;
#pragma unroll
        for (int c = 0; c < 5; ++c) {
            int col = c0 + tx * 5 + c;
            if (col < DH) out[(size_t)row * DH + col] = acc[r][c];
        }
    }
}

// ---------------- k_red: h = hp0 + hp1; e2 = h . a2 ----------------
// grid 256 blocks x 256 threads, 8 rows/block, 32 lanes/row
__global__ __launch_bounds__(256) void k_red(
    const float* __restrict__ HP, const float* __restrict__ A,
    float* __restrict__ H, float* __restrict__ E2)
{
    int t = threadIdx.x;
    int row = blockIdx.x * 8 + (t >> 5);
    int lane = t & 31;
    const float* p0 = HP + (size_t)row * DH;
    const float* p1 = HP + (size_t)(2048 * DH) + (size_t)row * DH;
    float acc = 0.f;
    for (int k = lane; k < DH; k += 32) {
        float hv = p0[k] + p1[k];
        H[(size_t)row * DH + k] = hv;
        acc += hv * A[DH + k];
    }
#pragma unroll
    for (int o = 16; o >= 1; o >>= 1) acc += __shfl_xor(acc, o);
    if (lane == 0) E2[row] = acc;
}

// ---------------- k_attn: fused attention per (b,i) ----------------
__global__ __launch_bounds__(256) void k_attn(
    const float* __restrict__ EE,  // (B,L,L,DE) fp32
    const int* __restrict__ ADJ,   // (B,L,L) int32
    const float* __restrict__ H,   // (2048, 300) fp32
    const float* __restrict__ E2,  // (2048,)
    const float* __restrict__ CV, const float* __restrict__ C0,
    const float* __restrict__ VW, const int* __restrict__ VCOL,
    float* __restrict__ OUT)
{
    __shared__ float eeb[L * DE];   // 51200 B: ee[b,i,:,:]
    __shared__ float hrow[DH];
    __shared__ float cl[DE];
    __shared__ float ef[L];
    __shared__ float att[L];
    __shared__ float red[4];

    int bid = blockIdx.x;           // b*128 + i
    int b = bid >> 7;
    int t = threadIdx.x;

    // stage ee row-block (coalesced float4: 3200 of them)
    const float4* src = (const float4*)(EE + (size_t)bid * (L * DE));
    float4* dst = (float4*)eeb;
    for (int idx = t; idx < 3200; idx += 256) dst[idx] = src[idx];
    // stage h row
    for (int k = t; k < DH; k += 256) hrow[k] = H[(size_t)bid * DH + k];
    if (t < DE) cl[t] = CV[t];
    __syncthreads();

    // ---- e_final[j] : 2 threads per j ----
    {
        int j = t >> 1, half = t & 1;
        const float* p = eeb + j * DE + half * 50;
        const float* cp = cl + half * 50;
        float s = 0.f;
#pragma unroll
        for (int q = 0; q < 50; ++q) s += p[q] * cp[q];
        s += __shfl_xor(s, 1);
        float ewv = 1.f / (1.f + expf(-(s + C0[0])));

        // e1 via band-sparse V row j
        int cm = VCOL[j];
        float e1 = 0.f;
#pragma unroll
        for (int u = 0; u < 4; ++u) {
            int c = cm + u; if (c > DH - 1) c = DH - 1;  // weight is 0 there
            e1 += VW[j * 4 + u] * hrow[c];
        }
        float e = e1 + E2[(size_t)b * L + j];
        e = (e > 0.f) ? e : 0.2f * e;
        float efv = (ADJ[(size_t)bid * L + j] > 0) ? e * ewv : -9.0e15f;
        if (half == 0) ef[j] = efv;
    }
    __syncthreads();

    // ---- softmax over j ----
    float v = (t < L) ? ef[t] : -3.0e38f;
#pragma unroll
    for (int o = 32; o >= 1; o >>= 1) v = fmaxf(v, __shfl_xor(v, o));
    int wid = t >> 6;
    if ((t & 63) == 0) red[wid] = v;
    __syncthreads();
    float mx = fmaxf(fmaxf(red[0], red[1]), fmaxf(red[2], red[3]));
    __syncthreads();
    float p = (t < L) ? expf(ef[t] - mx) : 0.f;
    v = p;
#pragma unroll
    for (int o = 32; o >= 1; o >>= 1) v += __shfl_xor(v, o);
    if ((t & 63) == 0) red[wid] = v;
    __syncthreads();
    float denom = red[0] + red[1] + red[2] + red[3];
    if (t < L) att[t] = p / denom;
    __syncthreads();

    // ---- out = h_row + att @ h[b] ----
    const float* Hb = H + (size_t)b * L * DH;
    for (int k = t; k < DH; k += 256) {
        float acc = hrow[k];
#pragma unroll 4
        for (int j = 0; j < L; ++j)
            acc = fmaf(att[j], Hb[(size_t)j * DH + k], acc);
        OUT[(size_t)bid * DH + k] = acc;
    }
}

extern "C" void kernel_launch(void* const* d_in, const int* in_sizes, int n_in,
                              void* d_out, int out_size, void* d_ws, size_t ws_size,
                              hipStream_t stream) {
    const float* X   = (const float*)d_in[0];
    const int*   ADJ = (const int*)d_in[1];
    const float* EE  = (const float*)d_in[2];
    const float* Wm  = (const float*)d_in[3];
    const float* A   = (const float*)d_in[4];
    const float* EMW = (const float*)d_in[5];
    const float* EMB = (const float*)d_in[6];
    const float* ELW = (const float*)d_in[7];
    const float* ELB = (const float*)d_in[8];
    float* OUT = (float*)d_out;

    float* ws = (float*)d_ws;
    float* HP   = ws;                    // 2 * 614400
    float* H    = ws + 1228800;          // 614400
    float* E2   = ws + 1843200;          // 2048
    float* CV   = ws + 1845248;          // 100
    float* C0   = ws + 1845348;          // 1 (+pad)
    float* VW   = ws + 1845352;          // 512
    int*   VCOL = (int*)(ws + 1845864);  // 128

    k_small<<<dim3(2), dim3(256), 0, stream>>>(A, EMW, EMB, ELW, ELB, CV, C0, VW, VCOL);
    k_gemm<<<dim3(4, 32, 2), dim3(256), 0, stream>>>(X, Wm, HP);
    k_red<<<dim3(256), dim3(256), 0, stream>>>(HP, A, H, E2);
    k_attn<<<dim3(2048), dim3(256), 0, stream>>>(EE, ADJ, H, E2, CV, C0, VW, VCOL, OUT);
}

// Round 3
// 120.496 us; speedup vs baseline: 1.4963x; 1.4963x over previous
//
#include <hip/hip_runtime.h>
#include <hip/hip_bf16.h>

// Problem: GraphAttentionLayer  B=16, L=128, DIN=768, DH=300, DE=100
// Device dtypes: all float tensors fp32, adj int32, out fp32.
//
// Pipeline:
//   k_small : c[d] = sum_k elw[k]*emw[k,d]; c0; band-sparse V (<=4 weights/row)
//   k_gemm  : h = x @ W   (split-K=2 partials, LDS-tiled vector-fp32 GEMM)
//   k_red   : h = hp0+hp1 ; e2[m] = h[m,:]·a[300:600]
//   k_attn  : per (b,i): e1 (sparse V), +e2[b,j], leakyrelu, *sigmoid(ee·c+c0),
//             mask by adj, softmax over j, out = h_row + att @ h[b]
//   R2->R3: k_attn was latency-bound (occ 17%, VALU 5%, HBM 6%). Dropped the
//   51.2KB single-use EE staging buffer (LDS 54.3KB -> 2.6KB, 2 -> 8 blocks/CU)
//   and widened PV ILP (4 accumulators).

#define L 128
#define DH 300
#define DIN 768
#define DE 100

// ---------------- k_small: c vector, c0, band-sparse V ----------------
__global__ __launch_bounds__(256) void k_small(
    const float* __restrict__ A,    // a (600,1)
    const float* __restrict__ EMW,  // edge_map_w (300,100)
    const float* __restrict__ EMB,  // edge_map_b (300,)
    const float* __restrict__ ELW,  // edge_lin_w (1,300)
    const float* __restrict__ ELB,  // edge_lin_b (1,)
    float* __restrict__ CV, float* __restrict__ C0,
    float* __restrict__ VW, int* __restrict__ VCOL)
{
    int t = threadIdx.x;
    if (blockIdx.x == 0) {
        if (t < DE) {
            float s = 0.f;
            for (int k = 0; k < DH; ++k)
                s += ELW[k] * EMW[k * DE + t];
            CV[t] = s;
        } else if (t == DE) {
            float s = 0.f;
            for (int k = 0; k < DH; ++k)
                s += ELW[k] * EMB[k];
            C0[0] = s + ELB[0];
        }
    } else {
        if (t < L) {
            int base = t * DH;
            int cm = base >> 7;           // // L, L=128
            float w0 = 0.f, w1 = 0.f, w2 = 0.f, w3 = 0.f;
            for (int j = 0; j < DH; ++j) {
                int u = ((base + j) >> 7) - cm;
                float av = A[j];
                w0 += (u == 0) ? av : 0.f;
                w1 += (u == 1) ? av : 0.f;
                w2 += (u == 2) ? av : 0.f;
                w3 += (u == 3) ? av : 0.f;
            }
            VCOL[t] = cm;
            VW[t * 4 + 0] = w0; VW[t * 4 + 1] = w1;
            VW[t * 4 + 2] = w2; VW[t * 4 + 3] = w3;
        }
    }
}

// ---------------- k_gemm: h = x @ W, split-K=2 ----------------
__global__ __launch_bounds__(256) void k_gemm(
    const float* __restrict__ X,   // (2048, 768)
    const float* __restrict__ Wm,  // (768, 300)
    float* __restrict__ HP)        // 2 x (2048*300) fp32 partials
{
    __shared__ float As[32 * 65];     // As[k*65 + row], padded
    __shared__ float Bs[32 * 80];     // Bs[k*80 + col]
    int t = threadIdx.x;
    int ty = t >> 4, tx = t & 15;
    int r0 = blockIdx.y * 64;
    int c0 = blockIdx.x * 80;
    int kz = blockIdx.z;
    int kbase = kz * 384;

    float acc[4][5];
#pragma unroll
    for (int r = 0; r < 4; ++r)
#pragma unroll
        for (int c = 0; c < 5; ++c) acc[r][c] = 0.f;

    for (int ks = 0; ks < 384; ks += 32) {
        int kk = kbase + ks;
#pragma unroll
        for (int s = 0; s < 8; ++s) {
            int idx = t + 256 * s;
            int row = idx >> 5, k = idx & 31;
            As[k * 65 + row] = X[(size_t)(r0 + row) * DIN + kk + k];
        }
#pragma unroll
        for (int s = 0; s < 10; ++s) {
            int idx = t + 256 * s;
            int k = idx / 80, c = idx % 80;
            int col = c0 + c;
            Bs[k * 80 + c] = (col < DH) ? Wm[(size_t)(kk + k) * DH + col] : 0.f;
        }
        __syncthreads();
#pragma unroll
        for (int k = 0; k < 32; ++k) {
            float av[4], bv[5];
#pragma unroll
            for (int r = 0; r < 4; ++r) av[r] = As[k * 65 + ty * 4 + r];
#pragma unroll
            for (int c = 0; c < 5; ++c) bv[c] = Bs[k * 80 + tx * 5 + c];
#pragma unroll
            for (int r = 0; r < 4; ++r)
#pragma unroll
                for (int c = 0; c < 5; ++c)
                    acc[r][c] = fmaf(av[r], bv[c], acc[r][c]);
        }
        __syncthreads();
    }
    float* out = HP + (size_t)kz * (2048 * DH);
#pragma unroll
    for (int r = 0; r < 4; ++r) {
        int row = r0 + ty * 4 + r;
#pragma unroll
        for (int c = 0; c < 5; ++c) {
            int col = c0 + tx * 5 + c;
            if (col < DH) out[(size_t)row * DH + col] = acc[r][c];
        }
    }
}

// ---------------- k_red: h = hp0 + hp1; e2 = h . a2 ----------------
__global__ __launch_bounds__(256) void k_red(
    const float* __restrict__ HP, const float* __restrict__ A,
    float* __restrict__ H, float* __restrict__ E2)
{
    int t = threadIdx.x;
    int row = blockIdx.x * 8 + (t >> 5);
    int lane = t & 31;
    const float* p0 = HP + (size_t)row * DH;
    const float* p1 = HP + (size_t)(2048 * DH) + (size_t)row * DH;
    float acc = 0.f;
    for (int k = lane; k < DH; k += 32) {
        float hv = p0[k] + p1[k];
        H[(size_t)row * DH + k] = hv;
        acc += hv * A[DH + k];
    }
#pragma unroll
    for (int o = 16; o >= 1; o >>= 1) acc += __shfl_xor(acc, o);
    if (lane == 0) E2[row] = acc;
}

// ---------------- k_attn: fused attention per (b,i), no EE staging ----------------
__global__ __launch_bounds__(256) void k_attn(
    const float* __restrict__ EE,  // (B,L,L,DE) fp32
    const int* __restrict__ ADJ,   // (B,L,L) int32
    const float* __restrict__ H,   // (2048, 300) fp32
    const float* __restrict__ E2,  // (2048,)
    const float* __restrict__ CV, const float* __restrict__ C0,
    const float* __restrict__ VW, const int* __restrict__ VCOL,
    float* __restrict__ OUT)
{
    __shared__ float hrow[DH];
    __shared__ float cl[DE];
    __shared__ float ef[L];
    __shared__ float att[L];
    __shared__ float red[4];

    int bid = blockIdx.x;           // b*128 + i
    int b = bid >> 7;
    int t = threadIdx.x;

    // stage h row + c vector (tiny)
    for (int k = t; k < DH; k += 256) hrow[k] = H[(size_t)bid * DH + k];
    if (t < DE) cl[t] = CV[t];
    __syncthreads();

    // ---- e_final[j] : 2 threads per j, EE read direct from global ----
    {
        int j = t >> 1, half = t & 1;
        const float2* p = (const float2*)(EE + (size_t)bid * (L * DE) + j * DE + half * 50);
        const float* cp = cl + half * 50;
        float s = 0.f;
#pragma unroll
        for (int q = 0; q < 25; ++q) {
            float2 v = p[q];
            s = fmaf(v.x, cp[2 * q], s);
            s = fmaf(v.y, cp[2 * q + 1], s);
        }
        s += __shfl_xor(s, 1);
        float ewv = 1.f / (1.f + expf(-(s + C0[0])));

        // e1 via band-sparse V row j
        int cm = VCOL[j];
        float e1 = 0.f;
#pragma unroll
        for (int u = 0; u < 4; ++u) {
            int c = cm + u; if (c > DH - 1) c = DH - 1;  // weight is 0 there
            e1 += VW[j * 4 + u] * hrow[c];
        }
        float e = e1 + E2[(size_t)b * L + j];
        e = (e > 0.f) ? e : 0.2f * e;
        float efv = (ADJ[(size_t)bid * L + j] > 0) ? e * ewv : -9.0e15f;
        if (half == 0) ef[j] = efv;
    }
    __syncthreads();

    // ---- softmax over j ----
    float v = (t < L) ? ef[t] : -3.0e38f;
#pragma unroll
    for (int o = 32; o >= 1; o >>= 1) v = fmaxf(v, __shfl_xor(v, o));
    int wid = t >> 6;
    if ((t & 63) == 0) red[wid] = v;
    __syncthreads();
    float mx = fmaxf(fmaxf(red[0], red[1]), fmaxf(red[2], red[3]));
    __syncthreads();
    float p = (t < L) ? expf(ef[t] - mx) : 0.f;
    v = p;
#pragma unroll
    for (int o = 32; o >= 1; o >>= 1) v += __shfl_xor(v, o);
    if ((t & 63) == 0) red[wid] = v;
    __syncthreads();
    float denom = red[0] + red[1] + red[2] + red[3];
    if (t < L) att[t] = p / denom;
    __syncthreads();

    // ---- out = h_row + att @ h[b], 4 independent accumulators ----
    const float* Hb = H + (size_t)b * L * DH;
    for (int k = t; k < DH; k += 256) {
        float a0 = hrow[k], a1 = 0.f, a2 = 0.f, a3 = 0.f;
#pragma unroll 4
        for (int j = 0; j < L; j += 4) {
            a0 = fmaf(att[j + 0], Hb[(size_t)(j + 0) * DH + k], a0);
            a1 = fmaf(att[j + 1], Hb[(size_t)(j + 1) * DH + k], a1);
            a2 = fmaf(att[j + 2], Hb[(size_t)(j + 2) * DH + k], a2);
            a3 = fmaf(att[j + 3], Hb[(size_t)(j + 3) * DH + k], a3);
        }
        OUT[(size_t)bid * DH + k] = (a0 + a1) + (a2 + a3);
    }
}

extern "C" void kernel_launch(void* const* d_in, const int* in_sizes, int n_in,
                              void* d_out, int out_size, void* d_ws, size_t ws_size,
                              hipStream_t stream) {
    const float* X   = (const float*)d_in[0];
    const int*   ADJ = (const int*)d_in[1];
    const float* EE  = (const float*)d_in[2];
    const float* Wm  = (const float*)d_in[3];
    const float* A   = (const float*)d_in[4];
    const float* EMW = (const float*)d_in[5];
    const float* EMB = (const float*)d_in[6];
    const float* ELW = (const float*)d_in[7];
    const float* ELB = (const float*)d_in[8];
    float* OUT = (float*)d_out;

    float* ws = (float*)d_ws;
    float* HP   = ws;                    // 2 * 614400
    float* H    = ws + 1228800;          // 614400
    float* E2   = ws + 1843200;          // 2048
    float* CV   = ws + 1845248;          // 100
    float* C0   = ws + 1845348;          // 1 (+pad)
    float* VW   = ws + 1845352;          // 512
    int*   VCOL = (int*)(ws + 1845864);  // 128

    k_small<<<dim3(2), dim3(256), 0, stream>>>(A, EMW, EMB, ELW, ELB, CV, C0, VW, VCOL);
    k_gemm<<<dim3(4, 32, 2), dim3(256), 0, stream>>>(X, Wm, HP);
    k_red<<<dim3(256), dim3(256), 0, stream>>>(HP, A, H, E2);
    k_attn<<<dim3(2048), dim3(256), 0, stream>>>(EE, ADJ, H, E2, CV, C0, VW, VCOL, OUT);
}

// Round 4
// 87.979 us; speedup vs baseline: 2.0494x; 1.3696x over previous
//
#include <hip/hip_runtime.h>
#include <hip/hip_bf16.h>

// Problem: GraphAttentionLayer  B=16, L=128, DIN=768, DH=300, DE=100
// Device dtypes: all float tensors fp32, adj int32, out fp32.
//
// Pipeline:
//   k_small : c[d] = sum_k elw[k]*emw[k,d]; c0; band-sparse V (<=4 weights/row)
//   k_gemm  : h = x @ W   (split-K=4, tile 32x80, micro 2x5, 1024 blocks)
//   k_red   : h = sum of 4 partials ; e2[m] = h[m,:]·a[300:600]  (float4)
//   k_attn  : per (b,i): e1 (sparse V), +e2[b,j], leakyrelu, *sigmoid(ee·c+c0),
//             mask by adj, softmax over j, out = h_row + att @ h[b]
//   R3->R4: k_gemm was starvation-bound (256 blocks = 1/CU, occ 11%, VALU 14%).
//   Split-K 4 + tile 32x80 micro 2x5 -> 1024 blocks, ~16 waves/CU.

#define L 128
#define DH 300
#define DIN 768
#define DE 100
#define KSL 4
#define MROWS 2048

// ---------------- k_small: c vector, c0, band-sparse V ----------------
__global__ __launch_bounds__(256) void k_small(
    const float* __restrict__ A,    // a (600,1)
    const float* __restrict__ EMW,  // edge_map_w (300,100)
    const float* __restrict__ EMB,  // edge_map_b (300,)
    const float* __restrict__ ELW,  // edge_lin_w (1,300)
    const float* __restrict__ ELB,  // edge_lin_b (1,)
    float* __restrict__ CV, float* __restrict__ C0,
    float* __restrict__ VW, int* __restrict__ VCOL)
{
    int t = threadIdx.x;
    if (blockIdx.x == 0) {
        if (t < DE) {
            float s = 0.f;
            for (int k = 0; k < DH; ++k)
                s += ELW[k] * EMW[k * DE + t];
            CV[t] = s;
        } else if (t == DE) {
            float s = 0.f;
            for (int k = 0; k < DH; ++k)
                s += ELW[k] * EMB[k];
            C0[0] = s + ELB[0];
        }
    } else {
        if (t < L) {
            int base = t * DH;
            int cm = base >> 7;           // // L, L=128
            float w0 = 0.f, w1 = 0.f, w2 = 0.f, w3 = 0.f;
            for (int j = 0; j < DH; ++j) {
                int u = ((base + j) >> 7) - cm;
                float av = A[j];
                w0 += (u == 0) ? av : 0.f;
                w1 += (u == 1) ? av : 0.f;
                w2 += (u == 2) ? av : 0.f;
                w3 += (u == 3) ? av : 0.f;
            }
            VCOL[t] = cm;
            VW[t * 4 + 0] = w0; VW[t * 4 + 1] = w1;
            VW[t * 4 + 2] = w2; VW[t * 4 + 3] = w3;
        }
    }
}

// ---------------- k_gemm: h = x @ W, split-K=4 ----------------
// grid (4 colTiles, 64 rowTiles, 4 kSlices) = 1024 blocks, 256 threads
// tile 32 (M) x 80 (N), K-step 32, micro 2x5 per thread (16x16 thread grid)
__global__ __launch_bounds__(256) void k_gemm(
    const float* __restrict__ X,   // (2048, 768)
    const float* __restrict__ Wm,  // (768, 300)
    float* __restrict__ HP)        // KSL x (2048*300) fp32 partials
{
    __shared__ float As[32 * 33];     // [k][row] k-major, padded
    __shared__ float Bs[32 * 80];     // [k][col]
    int t = threadIdx.x;
    int ty = t >> 4, tx = t & 15;
    int r0 = blockIdx.y * 32;
    int c0 = blockIdx.x * 80;
    int kbase = blockIdx.z * (DIN / KSL);   // 192 per slice

    float acc[2][5];
#pragma unroll
    for (int r = 0; r < 2; ++r)
#pragma unroll
        for (int c = 0; c < 5; ++c) acc[r][c] = 0.f;

    for (int ks = 0; ks < DIN / KSL; ks += 32) {
        int kk = kbase + ks;
        // stage A tile 32x32 (k-major in LDS), coalesced over k
#pragma unroll
        for (int s = 0; s < 4; ++s) {
            int idx = t + 256 * s;
            int row = idx >> 5, k = idx & 31;
            As[k * 33 + row] = X[(size_t)(r0 + row) * DIN + kk + k];
        }
        // stage B tile 32x80 as float4 (640 float4s)
        for (int idx = t; idx < 640; idx += 256) {
            int k = idx / 20, c4 = idx % 20;
            int c = c4 * 4;
            int col = c0 + c;
            float4 v;
            if (col + 3 < DH) v = *(const float4*)(Wm + (size_t)(kk + k) * DH + col);
            else { v.x = 0.f; v.y = 0.f; v.z = 0.f; v.w = 0.f; }
            *(float4*)(Bs + k * 80 + c) = v;
        }
        __syncthreads();
#pragma unroll
        for (int k = 0; k < 32; ++k) {
            float av0 = As[k * 33 + ty * 2];
            float av1 = As[k * 33 + ty * 2 + 1];
            float bv[5];
#pragma unroll
            for (int c = 0; c < 5; ++c) bv[c] = Bs[k * 80 + tx * 5 + c];
#pragma unroll
            for (int c = 0; c < 5; ++c) {
                acc[0][c] = fmaf(av0, bv[c], acc[0][c]);
                acc[1][c] = fmaf(av1, bv[c], acc[1][c]);
            }
        }
        __syncthreads();
    }
    float* out = HP + (size_t)blockIdx.z * (MROWS * DH);
#pragma unroll
    for (int r = 0; r < 2; ++r) {
        int row = r0 + ty * 2 + r;
#pragma unroll
        for (int c = 0; c < 5; ++c) {
            int col = c0 + tx * 5 + c;
            if (col < DH) out[(size_t)row * DH + col] = acc[r][c];
        }
    }
}

// ---------------- k_red: h = sum HP[0..3]; e2 = h . a2 (float4) ----------------
// grid 256 blocks x 256 threads, 8 rows/block, 32 lanes/row
__global__ __launch_bounds__(256) void k_red(
    const float* __restrict__ HP, const float* __restrict__ A,
    float* __restrict__ H, float* __restrict__ E2)
{
    const size_t SL = (size_t)MROWS * DH;
    int t = threadIdx.x;
    int row = blockIdx.x * 8 + (t >> 5);
    int lane = t & 31;
    const float4* p0 = (const float4*)(HP + (size_t)row * DH);
    const float4* p1 = (const float4*)(HP + SL + (size_t)row * DH);
    const float4* p2 = (const float4*)(HP + 2 * SL + (size_t)row * DH);
    const float4* p3 = (const float4*)(HP + 3 * SL + (size_t)row * DH);
    const float4* a4 = (const float4*)(A + DH);
    float4* hout = (float4*)(H + (size_t)row * DH);
    float acc = 0.f;
    for (int k4 = lane; k4 < DH / 4; k4 += 32) {   // 75 float4s
        float4 v0 = p0[k4], v1 = p1[k4], v2 = p2[k4], v3 = p3[k4];
        float4 av = a4[k4];
        float4 hv;
        hv.x = (v0.x + v1.x) + (v2.x + v3.x);
        hv.y = (v0.y + v1.y) + (v2.y + v3.y);
        hv.z = (v0.z + v1.z) + (v2.z + v3.z);
        hv.w = (v0.w + v1.w) + (v2.w + v3.w);
        hout[k4] = hv;
        acc += hv.x * av.x + hv.y * av.y + hv.z * av.z + hv.w * av.w;
    }
#pragma unroll
    for (int o = 16; o >= 1; o >>= 1) acc += __shfl_xor(acc, o);
    if (lane == 0) E2[row] = acc;
}

// ---------------- k_attn: fused attention per (b,i), no EE staging ----------------
__global__ __launch_bounds__(256) void k_attn(
    const float* __restrict__ EE,  // (B,L,L,DE) fp32
    const int* __restrict__ ADJ,   // (B,L,L) int32
    const float* __restrict__ H,   // (2048, 300) fp32
    const float* __restrict__ E2,  // (2048,)
    const float* __restrict__ CV, const float* __restrict__ C0,
    const float* __restrict__ VW, const int* __restrict__ VCOL,
    float* __restrict__ OUT)
{
    __shared__ float hrow[DH];
    __shared__ float cl[DE];
    __shared__ float ef[L];
    __shared__ float att[L];
    __shared__ float red[4];

    int bid = blockIdx.x;           // b*128 + i
    int b = bid >> 7;
    int t = threadIdx.x;

    // stage h row + c vector (tiny)
    for (int k = t; k < DH; k += 256) hrow[k] = H[(size_t)bid * DH + k];
    if (t < DE) cl[t] = CV[t];
    __syncthreads();

    // ---- e_final[j] : 2 threads per j, EE read direct from global ----
    {
        int j = t >> 1, half = t & 1;
        const float2* p = (const float2*)(EE + (size_t)bid * (L * DE) + j * DE + half * 50);
        const float* cp = cl + half * 50;
        float s = 0.f;
#pragma unroll
        for (int q = 0; q < 25; ++q) {
            float2 v = p[q];
            s = fmaf(v.x, cp[2 * q], s);
            s = fmaf(v.y, cp[2 * q + 1], s);
        }
        s += __shfl_xor(s, 1);
        float ewv = 1.f / (1.f + expf(-(s + C0[0])));

        // e1 via band-sparse V row j
        int cm = VCOL[j];
        float e1 = 0.f;
#pragma unroll
        for (int u = 0; u < 4; ++u) {
            int c = cm + u; if (c > DH - 1) c = DH - 1;  // weight is 0 there
            e1 += VW[j * 4 + u] * hrow[c];
        }
        float e = e1 + E2[(size_t)b * L + j];
        e = (e > 0.f) ? e : 0.2f * e;
        float efv = (ADJ[(size_t)bid * L + j] > 0) ? e * ewv : -9.0e15f;
        if (half == 0) ef[j] = efv;
    }
    __syncthreads();

    // ---- softmax over j ----
    float v = (t < L) ? ef[t] : -3.0e38f;
#pragma unroll
    for (int o = 32; o >= 1; o >>= 1) v = fmaxf(v, __shfl_xor(v, o));
    int wid = t >> 6;
    if ((t & 63) == 0) red[wid] = v;
    __syncthreads();
    float mx = fmaxf(fmaxf(red[0], red[1]), fmaxf(red[2], red[3]));
    __syncthreads();
    float p = (t < L) ? expf(ef[t] - mx) : 0.f;
    v = p;
#pragma unroll
    for (int o = 32; o >= 1; o >>= 1) v += __shfl_xor(v, o);
    if ((t & 63) == 0) red[wid] = v;
    __syncthreads();
    float denom = red[0] + red[1] + red[2] + red[3];
    if (t < L) att[t] = p / denom;
    __syncthreads();

    // ---- out = h_row + att @ h[b], 4 independent accumulators ----
    const float* Hb = H + (size_t)b * L * DH;
    for (int k = t; k < DH; k += 256) {
        float a0 = hrow[k], a1 = 0.f, a2 = 0.f, a3 = 0.f;
#pragma unroll 4
        for (int j = 0; j < L; j += 4) {
            a0 = fmaf(att[j + 0], Hb[(size_t)(j + 0) * DH + k], a0);
            a1 = fmaf(att[j + 1], Hb[(size_t)(j + 1) * DH + k], a1);
            a2 = fmaf(att[j + 2], Hb[(size_t)(j + 2) * DH + k], a2);
            a3 = fmaf(att[j + 3], Hb[(size_t)(j + 3) * DH + k], a3);
        }
        OUT[(size_t)bid * DH + k] = (a0 + a1) + (a2 + a3);
    }
}

extern "C" void kernel_launch(void* const* d_in, const int* in_sizes, int n_in,
                              void* d_out, int out_size, void* d_ws, size_t ws_size,
                              hipStream_t stream) {
    const float* X   = (const float*)d_in[0];
    const int*   ADJ = (const int*)d_in[1];
    const float* EE  = (const float*)d_in[2];
    const float* Wm  = (const float*)d_in[3];
    const float* A   = (const float*)d_in[4];
    const float* EMW = (const float*)d_in[5];
    const float* EMB = (const float*)d_in[6];
    const float* ELW = (const float*)d_in[7];
    const float* ELB = (const float*)d_in[8];
    float* OUT = (float*)d_out;

    float* ws = (float*)d_ws;
    float* HP   = ws;                    // 4 * 614400 = 2457600
    float* H    = ws + 2457600;          // 614400
    float* E2   = ws + 3072000;          // 2048
    float* CV   = ws + 3074048;          // 100
    float* C0   = ws + 3074148;          // 1 (+pad)
    float* VW   = ws + 3074152;          // 512
    int*   VCOL = (int*)(ws + 3074664);  // 128

    k_small<<<dim3(2), dim3(256), 0, stream>>>(A, EMW, EMB, ELW, ELB, CV, C0, VW, VCOL);
    k_gemm<<<dim3(4, 64, 4), dim3(256), 0, stream>>>(X, Wm, HP);
    k_red<<<dim3(256), dim3(256), 0, stream>>>(HP, A, H, E2);
    k_attn<<<dim3(2048), dim3(256), 0, stream>>>(EE, ADJ, H, E2, CV, C0, VW, VCOL, OUT);
}

// Round 5
// 77.444 us; speedup vs baseline: 2.3282x; 1.1360x over previous
//
#include <hip/hip_runtime.h>
#include <hip/hip_bf16.h>

// Problem: GraphAttentionLayer  B=16, L=128, DIN=768, DH=300, DE=100
// Device dtypes: all float tensors fp32, adj int32, out fp32.
//
// Pipeline:
//   k_small : c[d] = sum_k elw[k]*emw[k,d]; c0; band-sparse V (<=4 weights/row)
//   k_gemm  : h = x @ W  (split-K=8, tile 64x64, micro 4x4, b128 LDS reads)
//   k_red   : h = sum of 8 partials ; e2[m] = h[m,:]·a[300:600]  (float4)
//   k_attn  : per (b,i): e1 (sparse V), +e2[b,j], leakyrelu, *sigmoid(ee·c+c0),
//             mask by adj, softmax over j, out = h_row + att @ h[b]
//   R4->R5: k_gemm was ~60us: 2x5 micro = 10 FMA per 7 LDS reads, latency-
//   dominated. Now 4x4 micro with k-major LDS -> 2 ds_read_b128 + 16 FMA per k,
//   1280 blocks (5/CU).

#define L 128
#define DH 300
#define DIN 768
#define DE 100
#define SPLITK 8
#define MROWS 2048
#define SL ((size_t)MROWS * DH)

// ---------------- k_small: c vector, c0, band-sparse V ----------------
__global__ __launch_bounds__(256) void k_small(
    const float* __restrict__ A,    // a (600,1)
    const float* __restrict__ EMW,  // edge_map_w (300,100)
    const float* __restrict__ EMB,  // edge_map_b (300,)
    const float* __restrict__ ELW,  // edge_lin_w (1,300)
    const float* __restrict__ ELB,  // edge_lin_b (1,)
    float* __restrict__ CV, float* __restrict__ C0,
    float* __restrict__ VW, int* __restrict__ VCOL)
{
    int t = threadIdx.x;
    if (blockIdx.x == 0) {
        if (t < DE) {
            float s = 0.f;
            for (int k = 0; k < DH; ++k)
                s += ELW[k] * EMW[k * DE + t];
            CV[t] = s;
        } else if (t == DE) {
            float s = 0.f;
            for (int k = 0; k < DH; ++k)
                s += ELW[k] * EMB[k];
            C0[0] = s + ELB[0];
        }
    } else {
        if (t < L) {
            int base = t * DH;
            int cm = base >> 7;           // // L, L=128
            float w0 = 0.f, w1 = 0.f, w2 = 0.f, w3 = 0.f;
            for (int j = 0; j < DH; ++j) {
                int u = ((base + j) >> 7) - cm;
                float av = A[j];
                w0 += (u == 0) ? av : 0.f;
                w1 += (u == 1) ? av : 0.f;
                w2 += (u == 2) ? av : 0.f;
                w3 += (u == 3) ? av : 0.f;
            }
            VCOL[t] = cm;
            VW[t * 4 + 0] = w0; VW[t * 4 + 1] = w1;
            VW[t * 4 + 2] = w2; VW[t * 4 + 3] = w3;
        }
    }
}

// ---------------- k_gemm: h = x @ W, split-K=8, tile 64x64, micro 4x4 ----------------
// grid (5 colTiles, 32 rowTiles, 8 kSlices) = 1280 blocks, 256 threads
__global__ __launch_bounds__(256) void k_gemm(
    const float* __restrict__ X,   // (2048, 768)
    const float* __restrict__ Wm,  // (768, 300)
    float* __restrict__ HP)        // SPLITK x (2048*300) fp32 partials
{
    __shared__ float As[32][68];   // [k][row], 16B-aligned row fragments
    __shared__ float Bs[32][68];   // [k][col]
    int t = threadIdx.x;
    int tx = t & 15;               // col group (4 cols each)
    int ty = t >> 4;               // row group (4 rows each)
    int r0 = blockIdx.y * 64;
    int c0 = blockIdx.x * 64;
    int kbase = blockIdx.z * (DIN / SPLITK);   // 96 per slice

    float acc[4][4];
#pragma unroll
    for (int r = 0; r < 4; ++r)
#pragma unroll
        for (int c = 0; c < 4; ++c) acc[r][c] = 0.f;

    for (int ks = 0; ks < DIN / SPLITK; ks += 32) {
        int kk = kbase + ks;
        // stage A: 64 rows x 32 k; float4 along k, scatter to k-major LDS
#pragma unroll
        for (int s = 0; s < 2; ++s) {
            int id = t + 256 * s;          // 0..511
            int row = id >> 3;             // 64 rows
            int k4 = id & 7;               // 8 float4 per row
            float4 v = *(const float4*)(X + (size_t)(r0 + row) * DIN + kk + k4 * 4);
            As[k4 * 4 + 0][row] = v.x;
            As[k4 * 4 + 1][row] = v.y;
            As[k4 * 4 + 2][row] = v.z;
            As[k4 * 4 + 3][row] = v.w;
        }
        // stage B: 32 k x 64 cols; float4 along col (Wm row-major)
#pragma unroll
        for (int s = 0; s < 2; ++s) {
            int id = t + 256 * s;          // 0..511
            int k = id >> 4;               // 32 k
            int c4 = id & 15;              // 16 float4 per k
            int col = c0 + c4 * 4;
            float4 v;
            if (col < DH) v = *(const float4*)(Wm + (size_t)(kk + k) * DH + col);
            else { v.x = 0.f; v.y = 0.f; v.z = 0.f; v.w = 0.f; }
            *(float4*)&Bs[k][c4 * 4] = v;
        }
        __syncthreads();
#pragma unroll
        for (int k = 0; k < 32; ++k) {
            float4 a = *(const float4*)&As[k][ty * 4];
            float4 b = *(const float4*)&Bs[k][tx * 4];
            acc[0][0] = fmaf(a.x, b.x, acc[0][0]);
            acc[0][1] = fmaf(a.x, b.y, acc[0][1]);
            acc[0][2] = fmaf(a.x, b.z, acc[0][2]);
            acc[0][3] = fmaf(a.x, b.w, acc[0][3]);
            acc[1][0] = fmaf(a.y, b.x, acc[1][0]);
            acc[1][1] = fmaf(a.y, b.y, acc[1][1]);
            acc[1][2] = fmaf(a.y, b.z, acc[1][2]);
            acc[1][3] = fmaf(a.y, b.w, acc[1][3]);
            acc[2][0] = fmaf(a.z, b.x, acc[2][0]);
            acc[2][1] = fmaf(a.z, b.y, acc[2][1]);
            acc[2][2] = fmaf(a.z, b.z, acc[2][2]);
            acc[2][3] = fmaf(a.z, b.w, acc[2][3]);
            acc[3][0] = fmaf(a.w, b.x, acc[3][0]);
            acc[3][1] = fmaf(a.w, b.y, acc[3][1]);
            acc[3][2] = fmaf(a.w, b.z, acc[3][2]);
            acc[3][3] = fmaf(a.w, b.w, acc[3][3]);
        }
        __syncthreads();
    }
    float* outp = HP + (size_t)blockIdx.z * SL;
    int col = c0 + tx * 4;
    if (col < DH) {
#pragma unroll
        for (int r = 0; r < 4; ++r) {
            int row = r0 + ty * 4 + r;
            float4 v; v.x = acc[r][0]; v.y = acc[r][1]; v.z = acc[r][2]; v.w = acc[r][3];
            *(float4*)(outp + (size_t)row * DH + col) = v;
        }
    }
}

// ---------------- k_red: h = sum HP[0..7]; e2 = h . a2 (float4) ----------------
// grid 256 blocks x 256 threads, 8 rows/block, 32 lanes/row
__global__ __launch_bounds__(256) void k_red(
    const float* __restrict__ HP, const float* __restrict__ A,
    float* __restrict__ H, float* __restrict__ E2)
{
    int t = threadIdx.x;
    int row = blockIdx.x * 8 + (t >> 5);
    int lane = t & 31;
    const float4* a4 = (const float4*)(A + DH);
    float4* hout = (float4*)(H + (size_t)row * DH);
    float acc = 0.f;
    for (int k4 = lane; k4 < DH / 4; k4 += 32) {   // 75 float4s
        float4 hv; hv.x = 0.f; hv.y = 0.f; hv.z = 0.f; hv.w = 0.f;
#pragma unroll
        for (int z = 0; z < SPLITK; ++z) {
            float4 v = ((const float4*)(HP + (size_t)z * SL + (size_t)row * DH))[k4];
            hv.x += v.x; hv.y += v.y; hv.z += v.z; hv.w += v.w;
        }
        float4 av = a4[k4];
        hout[k4] = hv;
        acc += hv.x * av.x + hv.y * av.y + hv.z * av.z + hv.w * av.w;
    }
#pragma unroll
    for (int o = 16; o >= 1; o >>= 1) acc += __shfl_xor(acc, o);
    if (lane == 0) E2[row] = acc;
}

// ---------------- k_attn: fused attention per (b,i), no EE staging ----------------
__global__ __launch_bounds__(256) void k_attn(
    const float* __restrict__ EE,  // (B,L,L,DE) fp32
    const int* __restrict__ ADJ,   // (B,L,L) int32
    const float* __restrict__ H,   // (2048, 300) fp32
    const float* __restrict__ E2,  // (2048,)
    const float* __restrict__ CV, const float* __restrict__ C0,
    const float* __restrict__ VW, const int* __restrict__ VCOL,
    float* __restrict__ OUT)
{
    __shared__ float hrow[DH];
    __shared__ float cl[DE];
    __shared__ float ef[L];
    __shared__ float att[L];
    __shared__ float red[4];

    int bid = blockIdx.x;           // b*128 + i
    int b = bid >> 7;
    int t = threadIdx.x;

    // stage h row + c vector (tiny)
    for (int k = t; k < DH; k += 256) hrow[k] = H[(size_t)bid * DH + k];
    if (t < DE) cl[t] = CV[t];
    __syncthreads();

    // ---- e_final[j] : 2 threads per j, EE read direct from global ----
    {
        int j = t >> 1, half = t & 1;
        const float2* p = (const float2*)(EE + (size_t)bid * (L * DE) + j * DE + half * 50);
        const float* cp = cl + half * 50;
        float s = 0.f;
#pragma unroll
        for (int q = 0; q < 25; ++q) {
            float2 v = p[q];
            s = fmaf(v.x, cp[2 * q], s);
            s = fmaf(v.y, cp[2 * q + 1], s);
        }
        s += __shfl_xor(s, 1);
        float ewv = 1.f / (1.f + expf(-(s + C0[0])));

        // e1 via band-sparse V row j
        int cm = VCOL[j];
        float e1 = 0.f;
#pragma unroll
        for (int u = 0; u < 4; ++u) {
            int c = cm + u; if (c > DH - 1) c = DH - 1;  // weight is 0 there
            e1 += VW[j * 4 + u] * hrow[c];
        }
        float e = e1 + E2[(size_t)b * L + j];
        e = (e > 0.f) ? e : 0.2f * e;
        float efv = (ADJ[(size_t)bid * L + j] > 0) ? e * ewv : -9.0e15f;
        if (half == 0) ef[j] = efv;
    }
    __syncthreads();

    // ---- softmax over j ----
    float v = (t < L) ? ef[t] : -3.0e38f;
#pragma unroll
    for (int o = 32; o >= 1; o >>= 1) v = fmaxf(v, __shfl_xor(v, o));
    int wid = t >> 6;
    if ((t & 63) == 0) red[wid] = v;
    __syncthreads();
    float mx = fmaxf(fmaxf(red[0], red[1]), fmaxf(red[2], red[3]));
    __syncthreads();
    float p = (t < L) ? expf(ef[t] - mx) : 0.f;
    v = p;
#pragma unroll
    for (int o = 32; o >= 1; o >>= 1) v += __shfl_xor(v, o);
    if ((t & 63) == 0) red[wid] = v;
    __syncthreads();
    float denom = red[0] + red[1] + red[2] + red[3];
    if (t < L) att[t] = p / denom;
    __syncthreads();

    // ---- out = h_row + att @ h[b], 4 independent accumulators ----
    const float* Hb = H + (size_t)b * L * DH;
    for (int k = t; k < DH; k += 256) {
        float a0 = hrow[k], a1 = 0.f, a2 = 0.f, a3 = 0.f;
#pragma unroll 4
        for (int j = 0; j < L; j += 4) {
            a0 = fmaf(att[j + 0], Hb[(size_t)(j + 0) * DH + k], a0);
            a1 = fmaf(att[j + 1], Hb[(size_t)(j + 1) * DH + k], a1);
            a2 = fmaf(att[j + 2], Hb[(size_t)(j + 2) * DH + k], a2);
            a3 = fmaf(att[j + 3], Hb[(size_t)(j + 3) * DH + k], a3);
        }
        OUT[(size_t)bid * DH + k] = (a0 + a1) + (a2 + a3);
    }
}

extern "C" void kernel_launch(void* const* d_in, const int* in_sizes, int n_in,
                              void* d_out, int out_size, void* d_ws, size_t ws_size,
                              hipStream_t stream) {
    const float* X   = (const float*)d_in[0];
    const int*   ADJ = (const int*)d_in[1];
    const float* EE  = (const float*)d_in[2];
    const float* Wm  = (const float*)d_in[3];
    const float* A   = (const float*)d_in[4];
    const float* EMW = (const float*)d_in[5];
    const float* EMB = (const float*)d_in[6];
    const float* ELW = (const float*)d_in[7];
    const float* ELB = (const float*)d_in[8];
    float* OUT = (float*)d_out;

    float* ws = (float*)d_ws;
    float* HP   = ws;                    // 8 * 614400 = 4915200
    float* H    = ws + 4915200;          // 614400
    float* E2   = ws + 5529600;          // 2048
    float* CV   = ws + 5531648;          // 100
    float* C0   = ws + 5531748;          // 4 (pad)
    float* VW   = ws + 5531752;          // 512
    int*   VCOL = (int*)(ws + 5532264);  // 128

    k_small<<<dim3(2), dim3(256), 0, stream>>>(A, EMW, EMB, ELW, ELB, CV, C0, VW, VCOL);
    k_gemm<<<dim3(5, 32, 8), dim3(256), 0, stream>>>(X, Wm, HP);
    k_red<<<dim3(256), dim3(256), 0, stream>>>(HP, A, H, E2);
    k_attn<<<dim3(2048), dim3(256), 0, stream>>>(EE, ADJ, H, E2, CV, C0, VW, VCOL, OUT);
}

// Round 6
// 72.678 us; speedup vs baseline: 2.4808x; 1.0656x over previous
//
#include <hip/hip_runtime.h>
#include <hip/hip_bf16.h>

// Problem: GraphAttentionLayer  B=16, L=128, DIN=768, DH=300, DE=100
// Device dtypes: all float tensors fp32, adj int32, out fp32.
//
// Pipeline:
//   k_small : c[d] = sum_k elw[k]*emw[k,d]; c0; band-sparse V (<=4 weights/row)
//   k_cvt   : W (768x300 fp32) -> WT (320x768 bf16, zero-padded cols)
//   k_gemm  : h = x @ W via v_mfma_f32_16x16x32_bf16, tile 64x64, split-K=4
//   k_red   : h = sum of 4 partials ; e2[m] = h[m,:]·a[300:600]  (float4)
//   k_attn  : per (b,i): e1 (sparse V), +e2[b,j], leakyrelu, *sigmoid(ee·c+c0),
//             mask by adj, softmax over j, out = h_row + att @ h[b]
//   R5->R6: vector-FMA gemm stuck ~50us across two restructures (latency chain
//   ds_read->FMA). Switched to bf16 MFMA (error budget: thr 0.1025, bf16 adds
//   ~0.005). A: row=lane&15,k=(lane>>4)*8+j; B: col=lane&15; D: col=lane&15,
//   row=(lane>>4)*4+reg (m89-verified mapping).

#define L 128
#define DH 300
#define DIN 768
#define DE 100
#define SPLITK 4
#define MROWS 2048
#define SL ((size_t)MROWS * DH)

typedef __bf16 bf16x8 __attribute__((ext_vector_type(8)));
typedef float f32x4 __attribute__((ext_vector_type(4)));
typedef unsigned short ushort_t;

__device__ __forceinline__ ushort_t f2bf(float f) {
    __bf16 h = (__bf16)f;
    ushort_t u;
    __builtin_memcpy(&u, &h, 2);
    return u;
}

// ---------------- k_small: c vector, c0, band-sparse V ----------------
__global__ __launch_bounds__(256) void k_small(
    const float* __restrict__ A,    // a (600,1)
    const float* __restrict__ EMW,  // edge_map_w (300,100)
    const float* __restrict__ EMB,  // edge_map_b (300,)
    const float* __restrict__ ELW,  // edge_lin_w (1,300)
    const float* __restrict__ ELB,  // edge_lin_b (1,)
    float* __restrict__ CV, float* __restrict__ C0,
    float* __restrict__ VW, int* __restrict__ VCOL)
{
    int t = threadIdx.x;
    if (blockIdx.x == 0) {
        if (t < DE) {
            float s = 0.f;
            for (int k = 0; k < DH; ++k)
                s += ELW[k] * EMW[k * DE + t];
            CV[t] = s;
        } else if (t == DE) {
            float s = 0.f;
            for (int k = 0; k < DH; ++k)
                s += ELW[k] * EMB[k];
            C0[0] = s + ELB[0];
        }
    } else {
        if (t < L) {
            int base = t * DH;
            int cm = base >> 7;           // // L, L=128
            float w0 = 0.f, w1 = 0.f, w2 = 0.f, w3 = 0.f;
            for (int j = 0; j < DH; ++j) {
                int u = ((base + j) >> 7) - cm;
                float av = A[j];
                w0 += (u == 0) ? av : 0.f;
                w1 += (u == 1) ? av : 0.f;
                w2 += (u == 2) ? av : 0.f;
                w3 += (u == 3) ? av : 0.f;
            }
            VCOL[t] = cm;
            VW[t * 4 + 0] = w0; VW[t * 4 + 1] = w1;
            VW[t * 4 + 2] = w2; VW[t * 4 + 3] = w3;
        }
    }
}

// ---------------- k_cvt: WT[c][k] = bf16(W[k][c]), c<320 (zero-pad c>=300) ----------------
// grid (12 k-tiles, 5 c-tiles), 256 threads; LDS transpose
__global__ __launch_bounds__(256) void k_cvt(
    const float* __restrict__ Wm, ushort_t* __restrict__ WT)
{
    __shared__ float tile[64][65];
    int k0 = blockIdx.x * 64;
    int c0 = blockIdx.y * 64;
    int t = threadIdx.x;
#pragma unroll
    for (int s = 0; s < 16; ++s) {
        int idx = t + 256 * s;         // 0..4095
        int kr = idx >> 6, cc = idx & 63;
        int c = c0 + cc;
        tile[kr][cc] = (c < DH) ? Wm[(size_t)(k0 + kr) * DH + c] : 0.f;
    }
    __syncthreads();
#pragma unroll
    for (int s = 0; s < 16; ++s) {
        int idx = t + 256 * s;
        int c = idx >> 6, kr = idx & 63;
        WT[(size_t)(c0 + c) * DIN + k0 + kr] = f2bf(tile[kr][c]);
    }
}

// ---------------- k_gemm: h = x @ W via MFMA bf16 ----------------
// grid (5 colTiles, 32 rowTiles, 4 kSlices) = 640 blocks, 256 threads (4 waves)
// block tile 64x64, K-slice 192, K-step 64 (2 MFMA-K per step)
__global__ __launch_bounds__(256) void k_gemm(
    const float* __restrict__ X,       // (2048, 768) fp32
    const ushort_t* __restrict__ WT,   // (320, 768) bf16, transposed W
    float* __restrict__ HP)            // SPLITK x (2048*300) fp32 partials
{
    __shared__ ushort_t As[64 * 72];   // [row][k], stride 72 bf16 = 144 B
    __shared__ ushort_t Bs[64 * 72];   // [col][k]
    int t = threadIdx.x;
    int w = t >> 6;                    // wave 0..3: owns rows w*16
    int lane = t & 63;
    int lr = lane & 15;                // row/col within 16-tile
    int lk = lane >> 4;                // k-group (8 bf16 each)
    int r0 = blockIdx.y * 64;
    int c0 = blockIdx.x * 64;
    int kbase = blockIdx.z * (DIN / SPLITK);   // 192 per slice

    f32x4 acc[4];
#pragma unroll
    for (int ct = 0; ct < 4; ++ct) acc[ct] = (f32x4){0.f, 0.f, 0.f, 0.f};

    // staging roles (whole block): row/col = t>>2, kq = (t&3)*16
    int srow = t >> 2, skq = (t & 3) * 16;

    for (int step = 0; step < 3; ++step) {
        int kk = kbase + step * 64;
        // stage A: X[r0+srow][kk+skq .. +16) fp32 -> bf16
        {
            const float4* xs = (const float4*)(X + (size_t)(r0 + srow) * DIN + kk + skq);
            float4 f0 = xs[0], f1 = xs[1], f2 = xs[2], f3 = xs[3];
            bf16x8 v0, v1;
            v0[0] = (__bf16)f0.x; v0[1] = (__bf16)f0.y; v0[2] = (__bf16)f0.z; v0[3] = (__bf16)f0.w;
            v0[4] = (__bf16)f1.x; v0[5] = (__bf16)f1.y; v0[6] = (__bf16)f1.z; v0[7] = (__bf16)f1.w;
            v1[0] = (__bf16)f2.x; v1[1] = (__bf16)f2.y; v1[2] = (__bf16)f2.z; v1[3] = (__bf16)f2.w;
            v1[4] = (__bf16)f3.x; v1[5] = (__bf16)f3.y; v1[6] = (__bf16)f3.z; v1[7] = (__bf16)f3.w;
            *(bf16x8*)&As[srow * 72 + skq] = v0;
            *(bf16x8*)&As[srow * 72 + skq + 8] = v1;
        }
        // stage B: WT[c0+srow][kk+skq .. +16) bf16 direct copy
        {
            const uint4* wp = (const uint4*)(WT + (size_t)(c0 + srow) * DIN + kk + skq);
            uint4 u0 = wp[0], u1 = wp[1];
            *(uint4*)&Bs[srow * 72 + skq] = u0;
            *(uint4*)&Bs[srow * 72 + skq + 8] = u1;
        }
        __syncthreads();
#pragma unroll
        for (int k2 = 0; k2 < 2; ++k2) {
            bf16x8 af = *(bf16x8*)&As[(w * 16 + lr) * 72 + k2 * 32 + lk * 8];
#pragma unroll
            for (int ct = 0; ct < 4; ++ct) {
                bf16x8 bf_ = *(bf16x8*)&Bs[(ct * 16 + lr) * 72 + k2 * 32 + lk * 8];
                acc[ct] = __builtin_amdgcn_mfma_f32_16x16x32_bf16(af, bf_, acc[ct], 0, 0, 0);
            }
        }
        __syncthreads();
    }
    // write partials: D[row=(lk*4+r)][col=lr] per 16x16 tile
    float* outp = HP + (size_t)blockIdx.z * SL;
#pragma unroll
    for (int ct = 0; ct < 4; ++ct) {
        int col = c0 + ct * 16 + lr;
        if (col < DH) {
#pragma unroll
            for (int r = 0; r < 4; ++r) {
                int row = r0 + w * 16 + lk * 4 + r;
                outp[(size_t)row * DH + col] = acc[ct][r];
            }
        }
    }
}

// ---------------- k_red: h = sum HP[0..3]; e2 = h . a2 (float4) ----------------
// grid 256 blocks x 256 threads, 8 rows/block, 32 lanes/row
__global__ __launch_bounds__(256) void k_red(
    const float* __restrict__ HP, const float* __restrict__ A,
    float* __restrict__ H, float* __restrict__ E2)
{
    int t = threadIdx.x;
    int row = blockIdx.x * 8 + (t >> 5);
    int lane = t & 31;
    const float4* a4 = (const float4*)(A + DH);
    float4* hout = (float4*)(H + (size_t)row * DH);
    float acc = 0.f;
    for (int k4 = lane; k4 < DH / 4; k4 += 32) {   // 75 float4s
        float4 hv; hv.x = 0.f; hv.y = 0.f; hv.z = 0.f; hv.w = 0.f;
#pragma unroll
        for (int z = 0; z < SPLITK; ++z) {
            float4 v = ((const float4*)(HP + (size_t)z * SL + (size_t)row * DH))[k4];
            hv.x += v.x; hv.y += v.y; hv.z += v.z; hv.w += v.w;
        }
        float4 av = a4[k4];
        hout[k4] = hv;
        acc += hv.x * av.x + hv.y * av.y + hv.z * av.z + hv.w * av.w;
    }
#pragma unroll
    for (int o = 16; o >= 1; o >>= 1) acc += __shfl_xor(acc, o);
    if (lane == 0) E2[row] = acc;
}

// ---------------- k_attn: fused attention per (b,i), no EE staging ----------------
__global__ __launch_bounds__(256) void k_attn(
    const float* __restrict__ EE,  // (B,L,L,DE) fp32
    const int* __restrict__ ADJ,   // (B,L,L) int32
    const float* __restrict__ H,   // (2048, 300) fp32
    const float* __restrict__ E2,  // (2048,)
    const float* __restrict__ CV, const float* __restrict__ C0,
    const float* __restrict__ VW, const int* __restrict__ VCOL,
    float* __restrict__ OUT)
{
    __shared__ float hrow[DH];
    __shared__ float cl[DE];
    __shared__ float ef[L];
    __shared__ float att[L];
    __shared__ float red[4];

    int bid = blockIdx.x;           // b*128 + i
    int b = bid >> 7;
    int t = threadIdx.x;

    // stage h row + c vector (tiny)
    for (int k = t; k < DH; k += 256) hrow[k] = H[(size_t)bid * DH + k];
    if (t < DE) cl[t] = CV[t];
    __syncthreads();

    // ---- e_final[j] : 2 threads per j, EE read direct from global ----
    {
        int j = t >> 1, half = t & 1;
        const float2* p = (const float2*)(EE + (size_t)bid * (L * DE) + j * DE + half * 50);
        const float* cp = cl + half * 50;
        float s = 0.f;
#pragma unroll
        for (int q = 0; q < 25; ++q) {
            float2 v = p[q];
            s = fmaf(v.x, cp[2 * q], s);
            s = fmaf(v.y, cp[2 * q + 1], s);
        }
        s += __shfl_xor(s, 1);
        float ewv = 1.f / (1.f + expf(-(s + C0[0])));

        // e1 via band-sparse V row j
        int cm = VCOL[j];
        float e1 = 0.f;
#pragma unroll
        for (int u = 0; u < 4; ++u) {
            int c = cm + u; if (c > DH - 1) c = DH - 1;  // weight is 0 there
            e1 += VW[j * 4 + u] * hrow[c];
        }
        float e = e1 + E2[(size_t)b * L + j];
        e = (e > 0.f) ? e : 0.2f * e;
        float efv = (ADJ[(size_t)bid * L + j] > 0) ? e * ewv : -9.0e15f;
        if (half == 0) ef[j] = efv;
    }
    __syncthreads();

    // ---- softmax over j ----
    float v = (t < L) ? ef[t] : -3.0e38f;
#pragma unroll
    for (int o = 32; o >= 1; o >>= 1) v = fmaxf(v, __shfl_xor(v, o));
    int wid = t >> 6;
    if ((t & 63) == 0) red[wid] = v;
    __syncthreads();
    float mx = fmaxf(fmaxf(red[0], red[1]), fmaxf(red[2], red[3]));
    __syncthreads();
    float p = (t < L) ? expf(ef[t] - mx) : 0.f;
    v = p;
#pragma unroll
    for (int o = 32; o >= 1; o >>= 1) v += __shfl_xor(v, o);
    if ((t & 63) == 0) red[wid] = v;
    __syncthreads();
    float denom = red[0] + red[1] + red[2] + red[3];
    if (t < L) att[t] = p / denom;
    __syncthreads();

    // ---- out = h_row + att @ h[b], 4 independent accumulators ----
    const float* Hb = H + (size_t)b * L * DH;
    for (int k = t; k < DH; k += 256) {
        float a0 = hrow[k], a1 = 0.f, a2 = 0.f, a3 = 0.f;
#pragma unroll 4
        for (int j = 0; j < L; j += 4) {
            a0 = fmaf(att[j + 0], Hb[(size_t)(j + 0) * DH + k], a0);
            a1 = fmaf(att[j + 1], Hb[(size_t)(j + 1) * DH + k], a1);
            a2 = fmaf(att[j + 2], Hb[(size_t)(j + 2) * DH + k], a2);
            a3 = fmaf(att[j + 3], Hb[(size_t)(j + 3) * DH + k], a3);
        }
        OUT[(size_t)bid * DH + k] = (a0 + a1) + (a2 + a3);
    }
}

extern "C" void kernel_launch(void* const* d_in, const int* in_sizes, int n_in,
                              void* d_out, int out_size, void* d_ws, size_t ws_size,
                              hipStream_t stream) {
    const float* X   = (const float*)d_in[0];
    const int*   ADJ = (const int*)d_in[1];
    const float* EE  = (const float*)d_in[2];
    const float* Wm  = (const float*)d_in[3];
    const float* A   = (const float*)d_in[4];
    const float* EMW = (const float*)d_in[5];
    const float* EMB = (const float*)d_in[6];
    const float* ELW = (const float*)d_in[7];
    const float* ELB = (const float*)d_in[8];
    float* OUT = (float*)d_out;

    float* ws = (float*)d_ws;
    float* HP   = ws;                    // 4 * 614400 = 2457600
    float* H    = ws + 2457600;          // 614400
    float* E2   = ws + 3072000;          // 2048
    float* CV   = ws + 3074048;          // 100
    float* C0   = ws + 3074148;          // 4 (pad)
    float* VW   = ws + 3074152;          // 512
    int*   VCOL = (int*)(ws + 3074664);  // 128
    ushort_t* WT = (ushort_t*)(ws + 3074816); // 320*768 bf16 = 122880 floats

    k_small<<<dim3(2), dim3(256), 0, stream>>>(A, EMW, EMB, ELW, ELB, CV, C0, VW, VCOL);
    k_cvt<<<dim3(12, 5), dim3(256), 0, stream>>>(Wm, WT);
    k_gemm<<<dim3(5, 32, SPLITK), dim3(256), 0, stream>>>(X, WT, HP);
    k_red<<<dim3(256), dim3(256), 0, stream>>>(HP, A, H, E2);
    k_attn<<<dim3(2048), dim3(256), 0, stream>>>(EE, ADJ, H, E2, CV, C0, VW, VCOL, OUT);
}